// Round 2
// baseline (550.835 us; speedup 1.0000x reference)
//
#include <hip/hip_runtime.h>
#include <hip/hip_bf16.h>

typedef __bf16 bf16;
typedef bf16 bf16x2 __attribute__((ext_vector_type(2)));
typedef bf16 bf16x4 __attribute__((ext_vector_type(4)));
typedef bf16 bf16x8 __attribute__((ext_vector_type(8)));
typedef float floatx4 __attribute__((ext_vector_type(4)));

#define MFMA_BF16(a, b, c) __builtin_amdgcn_mfma_f32_16x16x32_bf16((a), (b), (c), 0, 0, 0)

// ---------------------------------------------------------------------------
// fp32 -> bf16 elementwise convert (8 els/thread)
// ---------------------------------------------------------------------------
__global__ __launch_bounds__(256) void cvt_kernel(const float* __restrict__ in,
                                                  bf16* __restrict__ out, int n8) {
    int idx = blockIdx.x * 256 + threadIdx.x;
    if (idx >= n8) return;
    const float* src = in + (size_t)idx * 8;
    float4 f0 = *(const float4*)src;
    float4 f1 = *(const float4*)(src + 4);
    bf16x8 v = {(bf16)f0.x, (bf16)f0.y, (bf16)f0.z, (bf16)f0.w,
                (bf16)f1.x, (bf16)f1.y, (bf16)f1.z, (bf16)f1.w};
    *(bf16x8*)(out + (size_t)idx * 8) = v;
}

// ---------------------------------------------------------------------------
// fp32 [R][C] -> bf16 [C][R] transpose (32x32 LDS tiles)
// ---------------------------------------------------------------------------
__global__ __launch_bounds__(256) void trans_kernel(const float* __restrict__ in,
                                                    bf16* __restrict__ out, int R, int C) {
    __shared__ float tile[32][33];
    const int t = threadIdx.x;
    const int r0 = blockIdx.y * 32, c0 = blockIdx.x * 32;
    int r = t >> 3, c4 = (t & 7) * 4;
    float4 v = *(const float4*)&in[(size_t)(r0 + r) * C + c0 + c4];
    tile[r][c4 + 0] = v.x; tile[r][c4 + 1] = v.y;
    tile[r][c4 + 2] = v.z; tile[r][c4 + 3] = v.w;
    __syncthreads();
    int rp = t >> 3, cp = (t & 7) * 4;
    bf16x4 w = {(bf16)tile[cp + 0][rp], (bf16)tile[cp + 1][rp],
                (bf16)tile[cp + 2][rp], (bf16)tile[cp + 3][rp]};
    *(bf16x4*)&out[(size_t)(c0 + rp) * R + r0 + cp] = w;
}

// ---------------------------------------------------------------------------
// bf16 [4096][1024] (rows=b*1024+j, cols=h*64+d) -> Vt[b][h][d][j]
// ---------------------------------------------------------------------------
__global__ __launch_bounds__(256) void vtrans_kernel(const bf16* __restrict__ in,
                                                     bf16* __restrict__ out) {
    __shared__ bf16 tile[32][36];
    const int t = threadIdx.x;
    const int r0 = blockIdx.y * 32, c0 = blockIdx.x * 32;  // r=m, c=h*64+d
    int r = t >> 3, c4 = (t & 7) * 4;
    bf16x4 v = *(const bf16x4*)&in[(size_t)(r0 + r) * 1024 + c0 + c4];
    tile[r][c4 + 0] = v[0]; tile[r][c4 + 1] = v[1];
    tile[r][c4 + 2] = v[2]; tile[r][c4 + 3] = v[3];
    __syncthreads();
    int rp = t >> 3, cp = (t & 7) * 4;
    int hd = c0 + rp;                 // (h*64+d)
    int b = r0 >> 10, j = (r0 & 1023) + cp;
    bf16x4 w = {tile[cp + 0][rp], tile[cp + 1][rp], tile[cp + 2][rp], tile[cp + 3][rp]};
    *(bf16x4*)&out[(size_t)(b * 1024 + hd) * 1024 + j] = w;
}

// ---------------------------------------------------------------------------
// Centered talking-heads weights, transposed for the attn A-frag:
// WtcT[g][k] = Wt[k][g] - mean_g'(Wt[k][g']) for k<16; WtcT[g][16..31] = 0.
// Layout [16][32] bf16 so a_wt = 16B load at [l15][quad*8] (quad>=2 -> zeros).
// ---------------------------------------------------------------------------
__global__ __launch_bounds__(256) void prep_wt_kernel(const float* __restrict__ Wt,
                                                      bf16* __restrict__ WtcT) {
    const int t = threadIdx.x;        // 256 threads: g = t>>4, k = t&15
    const int g = t >> 4, k = t & 15;
    float s = 0.f;
#pragma unroll
    for (int gg = 0; gg < 16; ++gg) s += Wt[k * 16 + gg];
    WtcT[g * 32 + k] = (bf16)(Wt[k * 16 + g] - s * 0.0625f);
    WtcT[g * 32 + 16 + k] = (bf16)0.f;
}

// ---------------------------------------------------------------------------
// m93-style 128x128 GEMM, BK=32, 256 threads (4 waves, 64x64/wave, 4x4 MFMA).
// A [M][1024] bf16 row-major; B [N][1024] bf16 (pre-transposed, n-major).
// MODE 0: C[m*N+n].  MODE 1 (KV): n<1024 -> C (K), n>=1024 -> V [m][n-1024].
// ---------------------------------------------------------------------------
template <int MODE>
__global__ __launch_bounds__(256) void gemm128(const bf16* __restrict__ A,
                                               const bf16* __restrict__ B,
                                               bf16* __restrict__ C,
                                               bf16* __restrict__ V, int N) {
    __shared__ bf16 As[128 * 40];
    __shared__ bf16 Bs[128 * 40];
    const int t = threadIdx.x;
    const int wv = t >> 6, lane = t & 63, quad = lane >> 4, l15 = lane & 15;
    const int wr = wv >> 1, wc = wv & 1;
    const int m0 = blockIdx.y * 128, n0 = blockIdx.x * 128;
    const int ra = t >> 1, kc = (t & 1) * 16;

    floatx4 acc[4][4] = {};

    for (int k0 = 0; k0 < 1024; k0 += 32) {
        bf16x8 a0 = *(const bf16x8*)&A[(size_t)(m0 + ra) * 1024 + k0 + kc];
        bf16x8 a1 = *(const bf16x8*)&A[(size_t)(m0 + ra) * 1024 + k0 + kc + 8];
        bf16x8 b0 = *(const bf16x8*)&B[(size_t)(n0 + ra) * 1024 + k0 + kc];
        bf16x8 b1 = *(const bf16x8*)&B[(size_t)(n0 + ra) * 1024 + k0 + kc + 8];
        __syncthreads();
        *(bf16x8*)&As[ra * 40 + kc] = a0;
        *(bf16x8*)&As[ra * 40 + kc + 8] = a1;
        *(bf16x8*)&Bs[ra * 40 + kc] = b0;
        *(bf16x8*)&Bs[ra * 40 + kc + 8] = b1;
        __syncthreads();
        bf16x8 af[4], bfr[4];
#pragma unroll
        for (int mt = 0; mt < 4; ++mt)
            af[mt] = *(bf16x8*)&As[(wr * 64 + mt * 16 + l15) * 40 + quad * 8];
#pragma unroll
        for (int nt = 0; nt < 4; ++nt)
            bfr[nt] = *(bf16x8*)&Bs[(wc * 64 + nt * 16 + l15) * 40 + quad * 8];
#pragma unroll
        for (int mt = 0; mt < 4; ++mt)
#pragma unroll
            for (int nt = 0; nt < 4; ++nt)
                acc[mt][nt] = MFMA_BF16(af[mt], bfr[nt], acc[mt][nt]);
    }
#pragma unroll
    for (int mt = 0; mt < 4; ++mt)
#pragma unroll
        for (int nt = 0; nt < 4; ++nt)
#pragma unroll
            for (int r = 0; r < 4; ++r) {
                int m = m0 + wr * 64 + mt * 16 + quad * 4 + r;
                int n = n0 + wc * 64 + nt * 16 + l15;
                bf16 val = (bf16)acc[mt][nt][r];
                if (MODE == 0) {
                    C[(size_t)m * N + n] = val;
                } else {
                    if (n < 1024) C[(size_t)m * 1024 + n] = val;
                    else          V[(size_t)m * 1024 + (n - 1024)] = val;
                }
            }
}

// ---------------------------------------------------------------------------
// Softmax denominators: L[b][h][i] = sum_j exp(q.k*scale).
// grid (i32-tiles=32, b=4, jsplit=16), 256 thr = 4 waves.
// hh-outer restructure: live state = qa(16)+se(8) regs -> <=64 VGPR, 8 w/SIMD.
// ---------------------------------------------------------------------------
__global__ __launch_bounds__(256, 8) void denom_kernel(const bf16* __restrict__ Qb,
                                                       const bf16* __restrict__ Kb,
                                                       float* __restrict__ L) {
    const int t = threadIdx.x;
    const int wv = t >> 6, lane = t & 63, quad = lane >> 4, l15 = lane & 15;
    const int i0 = blockIdx.x * 32, b = blockIdx.y, jz = blockIdx.z;
    const float scale = 0.125f;
    const bf16* Kbase = Kb + (size_t)b * 1024 * 1024;

    for (int hh = 0; hh < 4; ++hh) {
        const int h = wv * 4 + hh;
        bf16x8 qa[2][2];
#pragma unroll
        for (int it = 0; it < 2; ++it) {
            const bf16* qp = Qb + (size_t)(b * 1024 + i0 + it * 16 + l15) * 1024 +
                             h * 64 + quad * 8;
            qa[it][0] = *(const bf16x8*)qp;
            qa[it][1] = *(const bf16x8*)(qp + 32);
        }
        floatx4 se[2] = {};
#pragma unroll
        for (int jt = 0; jt < 4; ++jt) {
            int j = jz * 64 + jt * 16 + l15;
            const bf16* kp = Kbase + (size_t)j * 1024 + h * 64 + quad * 8;
            bf16x8 k0 = *(const bf16x8*)kp;
            bf16x8 k1 = *(const bf16x8*)(kp + 32);
#pragma unroll
            for (int it = 0; it < 2; ++it) {
                floatx4 c = {0.f, 0.f, 0.f, 0.f};
                c = MFMA_BF16(qa[it][0], k0, c);
                c = MFMA_BF16(qa[it][1], k1, c);
#pragma unroll
                for (int r = 0; r < 4; ++r) se[it][r] += __expf(c[r] * scale);
            }
        }
#pragma unroll
        for (int it = 0; it < 2; ++it)
#pragma unroll
            for (int r = 0; r < 4; ++r) {
                float s = se[it][r];
                s += __shfl_xor(s, 1); s += __shfl_xor(s, 2);
                s += __shfl_xor(s, 4); s += __shfl_xor(s, 8);
                if (l15 == 0)
                    atomicAdd(&L[(size_t)(b * 16 + h) * 1024 + i0 + it * 16 +
                                 quad * 4 + r], s);
            }
    }
}

// ---------------------------------------------------------------------------
// Main fused attention. grid (i16-tiles=64, b=4, jsplit=4), 512 thr = 8 waves,
// 2 heads/wave. Per 32-wide j-tile: S (MFMA) -> w=exp*invl -> Buf1 ->
// centered-Wt mix (MFMA, C[g][point]) + LN (2 shuffles) -> Buf2 -> PV (MFMA).
// Partial O atomicAdd'ed into out (out pre-zeroed).
// LDS = 20480 + 20480 = 40960 B exactly -> 4 blocks/CU (32 waves/CU).
// Buf2 row rot: idx(g,p) = g*640 + ((g>>2)&1)*8 + p  (keeps quad write-spread);
// the rot-hole Buf2[2560..2567] (row g=4, p<8 unused) doubles as the zero buf.
// ---------------------------------------------------------------------------
__global__ __launch_bounds__(512, 8) void attn_kernel(const bf16* __restrict__ Qb,
                                                      const bf16* __restrict__ Kb,
                                                      const bf16* __restrict__ Vt,
                                                      const float* __restrict__ L,
                                                      const bf16* __restrict__ WtcT,
                                                      const float* __restrict__ gamma,
                                                      const float* __restrict__ beta,
                                                      float* __restrict__ out) {
    __shared__ bf16 Buf1[512 * 20];        // [point p=i*32+jl][16 h + 4 pad]
    __shared__ bf16 Buf2[16 * 640];        // [g][rot(g) + i*40 + jl]
    const int t = threadIdx.x;
    const int wv = t >> 6, lane = t & 63, quad = lane >> 4, l15 = lane & 15;
    const int i0 = blockIdx.x * 16, b = blockIdx.y, jz = blockIdx.z;
    const float scale = 0.125f;

    if (t < 8) Buf2[2560 + t] = (bf16)0.f;   // zero region (never overwritten)
    const bf16* Zbuf = &Buf2[2560];

    // A-frag of centered Wt^T: one 16B load (quad>=2 slots are stored zeros).
    bf16x8 a_wt = *(const bf16x8*)&WtcT[l15 * 32 + quad * 8];
    float gq[4], bq[4];
#pragma unroll
    for (int r = 0; r < 4; ++r) { gq[r] = gamma[quad * 4 + r]; bq[r] = beta[quad * 4 + r]; }

    bf16x8 qa[2][2];
    float invl[2][4];
#pragma unroll
    for (int hh = 0; hh < 2; ++hh) {
        int h = wv * 2 + hh;
        const bf16* qp = Qb + (size_t)(b * 1024 + i0 + l15) * 1024 + h * 64 + quad * 8;
        qa[hh][0] = *(const bf16x8*)qp;
        qa[hh][1] = *(const bf16x8*)(qp + 32);
#pragma unroll
        for (int r = 0; r < 4; ++r)
            invl[hh][r] = 1.f / L[(size_t)(b * 16 + h) * 1024 + i0 + quad * 4 + r];
    }

    const bf16* Kbase = Kb + (size_t)b * 1024 * 1024;
    const bf16* Vbase = Vt + (size_t)b * 16 * 64 * 1024;
    floatx4 o[2][4] = {};

    for (int jt = 0; jt < 8; ++jt) {
        const int j0 = jz * 256 + jt * 32;
        // (a) S -> w -> Buf1 (packed bf16x2 for the wave's head pair)
#pragma unroll
        for (int ns = 0; ns < 2; ++ns) {
            floatx4 cw[2];
#pragma unroll
            for (int hh = 0; hh < 2; ++hh) {
                int h = wv * 2 + hh;
                const bf16* kp = Kbase + (size_t)(j0 + ns * 16 + l15) * 1024 + h * 64 + quad * 8;
                floatx4 c = {0.f, 0.f, 0.f, 0.f};
                c = MFMA_BF16(qa[hh][0], *(const bf16x8*)kp, c);
                c = MFMA_BF16(qa[hh][1], *(const bf16x8*)(kp + 32), c);
                cw[hh] = c;
            }
#pragma unroll
            for (int r = 0; r < 4; ++r) {
                bf16x2 pk = {(bf16)(__expf(cw[0][r] * scale) * invl[0][r]),
                             (bf16)(__expf(cw[1][r] * scale) * invl[1][r])};
                *(bf16x2*)&Buf1[((quad * 4 + r) * 32 + ns * 16 + l15) * 20 + wv * 2] = pk;
            }
        }
        __syncthreads();
        // (b) mix (C[g][point]) + LN over g (mean is exactly 0 by centering)
#pragma unroll
        for (int grp = 0; grp < 4; ++grp) {
            int gi = wv * 4 + grp, ig = gi >> 1, jb = (gi & 1) * 16;
            int p = ig * 32 + jb + l15;
            const bf16* src = (quad < 2) ? &Buf1[p * 20 + quad * 8] : Zbuf;
            floatx4 c = {0.f, 0.f, 0.f, 0.f};
            c = MFMA_BF16(a_wt, *(const bf16x8*)src, c);
            float s2 = c[0] * c[0] + c[1] * c[1] + c[2] * c[2] + c[3] * c[3];
            s2 += __shfl_xor(s2, 16);
            s2 += __shfl_xor(s2, 32);
            float rs = rsqrtf(s2 * 0.0625f + 1e-5f);
#pragma unroll
            for (int r = 0; r < 4; ++r) {
                float w2 = c[r] * rs * gq[r] + bq[r];
                Buf2[(quad * 4 + r) * 640 + (quad & 1) * 8 + ig * 40 + jb + l15] = (bf16)w2;
            }
        }
        __syncthreads();
        // (c) PV: O[i][d] += w2[i][jl] * V[jl][d]
#pragma unroll
        for (int hh = 0; hh < 2; ++hh) {
            int g = wv * 2 + hh;
            bf16x8 a = *(bf16x8*)&Buf2[g * 640 + ((g >> 2) & 1) * 8 + l15 * 40 + quad * 8];
#pragma unroll
            for (int dt = 0; dt < 4; ++dt) {
                const bf16* vp = Vbase + (size_t)(g * 64 + dt * 16 + l15) * 1024 + j0 + quad * 8;
                o[hh][dt] = MFMA_BF16(a, *(const bf16x8*)vp, o[hh][dt]);
            }
        }
    }
#pragma unroll
    for (int hh = 0; hh < 2; ++hh) {
        int g = wv * 2 + hh;
#pragma unroll
        for (int dt = 0; dt < 4; ++dt)
#pragma unroll
            for (int r = 0; r < 4; ++r)
                atomicAdd(&out[(size_t)(b * 1024 + i0 + quad * 4 + r) * 1024 +
                               g * 64 + dt * 16 + l15], o[hh][dt][r]);
    }
}

extern "C" void kernel_launch(void* const* d_in, const int* in_sizes, int n_in,
                              void* d_out, int out_size, void* d_ws, size_t ws_size,
                              hipStream_t stream) {
    const float* x     = (const float*)d_in[0];
    const float* ctx   = (const float*)d_in[1];
    const float* Wq    = (const float*)d_in[2];
    const float* Wkv   = (const float*)d_in[3];
    const float* Wt    = (const float*)d_in[4];
    const float* gamma = (const float*)d_in[5];
    const float* beta  = (const float*)d_in[6];
    float* out = (float*)d_out;

    // ws layout (bf16 els): xb 4M | ctxb 4M | WqT 1M | WkvT 2M | Qb 4M | Kb 4M |
    //                       Vr 4M | Vt 4M | L (64K fp32)   => ~54.25 MB
    // WtcT (512 bf16) reuses the head of Vr: Vr is dead after vtrans_kernel.
    bf16* xb   = (bf16*)d_ws;
    bf16* cb   = xb + (size_t)4 * 1024 * 1024;
    bf16* WqT  = cb + (size_t)4 * 1024 * 1024;
    bf16* WkvT = WqT + (size_t)1024 * 1024;
    bf16* Qb   = WkvT + (size_t)2048 * 1024;
    bf16* Kb   = Qb + (size_t)4 * 1024 * 1024;
    bf16* Vr   = Kb + (size_t)4 * 1024 * 1024;
    bf16* Vt   = Vr + (size_t)4 * 1024 * 1024;
    float* L   = (float*)(Vt + (size_t)4 * 1024 * 1024);
    bf16* WtcT = Vr;

    hipMemsetAsync(L, 0, (size_t)4 * 16 * 1024 * sizeof(float), stream);
    hipMemsetAsync(out, 0, (size_t)out_size * sizeof(float), stream);

    cvt_kernel<<<2048, 256, 0, stream>>>(x, xb, 524288);
    cvt_kernel<<<2048, 256, 0, stream>>>(ctx, cb, 524288);
    trans_kernel<<<dim3(32, 32), 256, 0, stream>>>(Wq, WqT, 1024, 1024);
    trans_kernel<<<dim3(64, 32), 256, 0, stream>>>(Wkv, WkvT, 1024, 2048);

    gemm128<0><<<dim3(8, 32), 256, 0, stream>>>(xb, WqT, Qb, nullptr, 1024);
    gemm128<1><<<dim3(16, 32), 256, 0, stream>>>(cb, WkvT, Kb, Vr, 2048);
    vtrans_kernel<<<dim3(32, 128), 256, 0, stream>>>(Vr, Vt);
    prep_wt_kernel<<<1, 256, 0, stream>>>(Wt, WtcT);

    denom_kernel<<<dim3(32, 4, 16), 256, 0, stream>>>(Qb, Kb, L);
    attn_kernel<<<dim3(64, 4, 4), 512, 0, stream>>>(Qb, Kb, Vt, L, WtcT, gamma, beta, out);
}

// Round 3
// 359.045 us; speedup vs baseline: 1.5342x; 1.5342x over previous
//
#include <hip/hip_runtime.h>
#include <hip/hip_bf16.h>

typedef __bf16 bf16;
typedef bf16 bf16x2 __attribute__((ext_vector_type(2)));
typedef bf16 bf16x4 __attribute__((ext_vector_type(4)));
typedef bf16 bf16x8 __attribute__((ext_vector_type(8)));
typedef float floatx4 __attribute__((ext_vector_type(4)));

#define MFMA_BF16(a, b, c) __builtin_amdgcn_mfma_f32_16x16x32_bf16((a), (b), (c), 0, 0, 0)

// ---------------------------------------------------------------------------
// fp32 -> bf16 elementwise convert (8 els/thread)
// ---------------------------------------------------------------------------
__global__ __launch_bounds__(256) void cvt_kernel(const float* __restrict__ in,
                                                  bf16* __restrict__ out, int n8) {
    int idx = blockIdx.x * 256 + threadIdx.x;
    if (idx >= n8) return;
    const float* src = in + (size_t)idx * 8;
    float4 f0 = *(const float4*)src;
    float4 f1 = *(const float4*)(src + 4);
    bf16x8 v = {(bf16)f0.x, (bf16)f0.y, (bf16)f0.z, (bf16)f0.w,
                (bf16)f1.x, (bf16)f1.y, (bf16)f1.z, (bf16)f1.w};
    *(bf16x8*)(out + (size_t)idx * 8) = v;
}

// ---------------------------------------------------------------------------
// fp32 [R][C] -> bf16 [C][R] transpose (32x32 LDS tiles)
// ---------------------------------------------------------------------------
__global__ __launch_bounds__(256) void trans_kernel(const float* __restrict__ in,
                                                    bf16* __restrict__ out, int R, int C) {
    __shared__ float tile[32][33];
    const int t = threadIdx.x;
    const int r0 = blockIdx.y * 32, c0 = blockIdx.x * 32;
    int r = t >> 3, c4 = (t & 7) * 4;
    float4 v = *(const float4*)&in[(size_t)(r0 + r) * C + c0 + c4];
    tile[r][c4 + 0] = v.x; tile[r][c4 + 1] = v.y;
    tile[r][c4 + 2] = v.z; tile[r][c4 + 3] = v.w;
    __syncthreads();
    int rp = t >> 3, cp = (t & 7) * 4;
    bf16x4 w = {(bf16)tile[cp + 0][rp], (bf16)tile[cp + 1][rp],
                (bf16)tile[cp + 2][rp], (bf16)tile[cp + 3][rp]};
    *(bf16x4*)&out[(size_t)(c0 + rp) * R + r0 + cp] = w;
}

// ---------------------------------------------------------------------------
// bf16 [4096][1024] (rows=b*1024+j, cols=h*64+d) -> Vt[b][h][d][j]
// ---------------------------------------------------------------------------
__global__ __launch_bounds__(256) void vtrans_kernel(const bf16* __restrict__ in,
                                                     bf16* __restrict__ out) {
    __shared__ bf16 tile[32][36];
    const int t = threadIdx.x;
    const int r0 = blockIdx.y * 32, c0 = blockIdx.x * 32;  // r=m, c=h*64+d
    int r = t >> 3, c4 = (t & 7) * 4;
    bf16x4 v = *(const bf16x4*)&in[(size_t)(r0 + r) * 1024 + c0 + c4];
    tile[r][c4 + 0] = v[0]; tile[r][c4 + 1] = v[1];
    tile[r][c4 + 2] = v[2]; tile[r][c4 + 3] = v[3];
    __syncthreads();
    int rp = t >> 3, cp = (t & 7) * 4;
    int hd = c0 + rp;                 // (h*64+d)
    int b = r0 >> 10, j = (r0 & 1023) + cp;
    bf16x4 w = {tile[cp + 0][rp], tile[cp + 1][rp], tile[cp + 2][rp], tile[cp + 3][rp]};
    *(bf16x4*)&out[(size_t)(b * 1024 + hd) * 1024 + j] = w;
}

// ---------------------------------------------------------------------------
// Centered talking-heads weights, transposed for the attn A-frag:
// WtcT[g][k] = Wt[k][g] - mean_g'(Wt[k][g']) for k<16; WtcT[g][16..31] = 0.
// Layout [16][32] bf16 so a_wt = 16B load at [l15][quad*8] (quad>=2 -> zeros).
// ---------------------------------------------------------------------------
__global__ __launch_bounds__(256) void prep_wt_kernel(const float* __restrict__ Wt,
                                                      bf16* __restrict__ WtcT) {
    const int t = threadIdx.x;        // 256 threads: g = t>>4, k = t&15
    const int g = t >> 4, k = t & 15;
    float s = 0.f;
#pragma unroll
    for (int gg = 0; gg < 16; ++gg) s += Wt[k * 16 + gg];
    WtcT[g * 32 + k] = (bf16)(Wt[k * 16 + g] - s * 0.0625f);
    WtcT[g * 32 + 16 + k] = (bf16)0.f;
}

// ---------------------------------------------------------------------------
// m93-style 128x128 GEMM, BK=32, 256 threads (4 waves, 64x64/wave, 4x4 MFMA).
// A [M][1024] bf16 row-major; B [N][1024] bf16 (pre-transposed, n-major).
// MODE 0: C[m*N+n].  MODE 1 (KV): n<1024 -> C (K), n>=1024 -> V [m][n-1024].
// ---------------------------------------------------------------------------
template <int MODE>
__global__ __launch_bounds__(256) void gemm128(const bf16* __restrict__ A,
                                               const bf16* __restrict__ B,
                                               bf16* __restrict__ C,
                                               bf16* __restrict__ V, int N) {
    __shared__ bf16 As[128 * 40];
    __shared__ bf16 Bs[128 * 40];
    const int t = threadIdx.x;
    const int wv = t >> 6, lane = t & 63, quad = lane >> 4, l15 = lane & 15;
    const int wr = wv >> 1, wc = wv & 1;
    const int m0 = blockIdx.y * 128, n0 = blockIdx.x * 128;
    const int ra = t >> 1, kc = (t & 1) * 16;

    floatx4 acc[4][4] = {};

    for (int k0 = 0; k0 < 1024; k0 += 32) {
        bf16x8 a0 = *(const bf16x8*)&A[(size_t)(m0 + ra) * 1024 + k0 + kc];
        bf16x8 a1 = *(const bf16x8*)&A[(size_t)(m0 + ra) * 1024 + k0 + kc + 8];
        bf16x8 b0 = *(const bf16x8*)&B[(size_t)(n0 + ra) * 1024 + k0 + kc];
        bf16x8 b1 = *(const bf16x8*)&B[(size_t)(n0 + ra) * 1024 + k0 + kc + 8];
        __syncthreads();
        *(bf16x8*)&As[ra * 40 + kc] = a0;
        *(bf16x8*)&As[ra * 40 + kc + 8] = a1;
        *(bf16x8*)&Bs[ra * 40 + kc] = b0;
        *(bf16x8*)&Bs[ra * 40 + kc + 8] = b1;
        __syncthreads();
        bf16x8 af[4], bfr[4];
#pragma unroll
        for (int mt = 0; mt < 4; ++mt)
            af[mt] = *(bf16x8*)&As[(wr * 64 + mt * 16 + l15) * 40 + quad * 8];
#pragma unroll
        for (int nt = 0; nt < 4; ++nt)
            bfr[nt] = *(bf16x8*)&Bs[(wc * 64 + nt * 16 + l15) * 40 + quad * 8];
#pragma unroll
        for (int mt = 0; mt < 4; ++mt)
#pragma unroll
            for (int nt = 0; nt < 4; ++nt)
                acc[mt][nt] = MFMA_BF16(af[mt], bfr[nt], acc[mt][nt]);
    }
#pragma unroll
    for (int mt = 0; mt < 4; ++mt)
#pragma unroll
        for (int nt = 0; nt < 4; ++nt)
#pragma unroll
            for (int r = 0; r < 4; ++r) {
                int m = m0 + wr * 64 + mt * 16 + quad * 4 + r;
                int n = n0 + wc * 64 + nt * 16 + l15;
                bf16 val = (bf16)acc[mt][nt][r];
                if (MODE == 0) {
                    C[(size_t)m * N + n] = val;
                } else {
                    if (n < 1024) C[(size_t)m * 1024 + n] = val;
                    else          V[(size_t)m * 1024 + (n - 1024)] = val;
                }
            }
}

// ---------------------------------------------------------------------------
// Softmax denominators: L[b][h][i] = sum_j exp(q.k*scale).
// grid (i32=32, b=4, jsplit=16) = 2048 blocks, 256 thr = 4 waves.
// XCD swizzle: chunk of 256 consecutive logical blocks per XCD so the K
// slices each XCD touches stay L2-resident.
// ---------------------------------------------------------------------------
__global__ __launch_bounds__(256, 4) void denom_kernel(const bf16* __restrict__ Qb,
                                                       const bf16* __restrict__ Kb,
                                                       float* __restrict__ L) {
    const int t = threadIdx.x;
    const int wv = t >> 6, lane = t & 63, quad = lane >> 4, l15 = lane & 15;
    // XCD-aware swizzle: n = dispatch order (x fastest); o = logical block.
    unsigned n = blockIdx.x + (blockIdx.y << 5) + (blockIdx.z << 7);   // 2048 total
    unsigned o = (n & 7) * 256 + (n >> 3);
    const int i0 = (o & 31) * 32;
    const int b  = (o >> 5) & 3;
    const int jz = o >> 7;
    const float scale = 0.125f;
    const bf16* Kbase = Kb + (size_t)b * 1024 * 1024;

    for (int hh = 0; hh < 4; ++hh) {
        const int h = wv * 4 + hh;
        bf16x8 qa[2][2];
#pragma unroll
        for (int it = 0; it < 2; ++it) {
            const bf16* qp = Qb + (size_t)(b * 1024 + i0 + it * 16 + l15) * 1024 +
                             h * 64 + quad * 8;
            qa[it][0] = *(const bf16x8*)qp;
            qa[it][1] = *(const bf16x8*)(qp + 32);
        }
        floatx4 se[2] = {};
#pragma unroll
        for (int jt = 0; jt < 4; ++jt) {
            int j = jz * 64 + jt * 16 + l15;
            const bf16* kp = Kbase + (size_t)j * 1024 + h * 64 + quad * 8;
            bf16x8 k0 = *(const bf16x8*)kp;
            bf16x8 k1 = *(const bf16x8*)(kp + 32);
#pragma unroll
            for (int it = 0; it < 2; ++it) {
                floatx4 c = {0.f, 0.f, 0.f, 0.f};
                c = MFMA_BF16(qa[it][0], k0, c);
                c = MFMA_BF16(qa[it][1], k1, c);
#pragma unroll
                for (int r = 0; r < 4; ++r) se[it][r] += __expf(c[r] * scale);
            }
        }
#pragma unroll
        for (int it = 0; it < 2; ++it)
#pragma unroll
            for (int r = 0; r < 4; ++r) {
                float s = se[it][r];
                s += __shfl_xor(s, 1); s += __shfl_xor(s, 2);
                s += __shfl_xor(s, 4); s += __shfl_xor(s, 8);
                if (l15 == 0)
                    atomicAdd(&L[(size_t)(b * 16 + h) * 1024 + i0 + it * 16 +
                                 quad * 4 + r], s);
            }
    }
}

// ---------------------------------------------------------------------------
// Main fused attention. Logical grid (i16=64, b=4, jsplit=2) = 512 blocks,
// 512 thr = 8 waves, 2 heads/wave. Per 32-wide j-tile: S (MFMA) ->
// w=exp*invl -> Buf1 -> centered-Wt mix (MFMA, C[g][point]) + LN (2 shuffles)
// -> Buf2 -> PV (MFMA). Partial O atomicAdd'ed into out (out pre-zeroed).
// XCD swizzle: 64 consecutive logical blocks (= one full i-sweep of a
// (b,jz) panel) per XCD; K+V panel = 2 MB fits the 4 MB per-XCD L2.
// LDS = 40960 B. launch_bounds (512,4): known-good codegen (no spills).
// ---------------------------------------------------------------------------
__global__ __launch_bounds__(512, 4) void attn_kernel(const bf16* __restrict__ Qb,
                                                      const bf16* __restrict__ Kb,
                                                      const bf16* __restrict__ Vt,
                                                      const float* __restrict__ L,
                                                      const bf16* __restrict__ WtcT,
                                                      const float* __restrict__ gamma,
                                                      const float* __restrict__ beta,
                                                      float* __restrict__ out) {
    __shared__ bf16 Buf1[512 * 20];        // [point p=i*32+jl][16 h + 4 pad]
    __shared__ bf16 Buf2[16 * 640];        // [g][rot(g) + i*40 + jl]
    const int t = threadIdx.x;
    const int wv = t >> 6, lane = t & 63, quad = lane >> 4, l15 = lane & 15;
    // XCD-aware swizzle (bijective: 512 = 8 * 64).
    unsigned n = blockIdx.x + (blockIdx.y << 6) + (blockIdx.z << 8);   // 512 total
    unsigned o_idx = (n & 7) * 64 + (n >> 3);
    const int i0 = (o_idx & 63) * 16;
    const int b  = (o_idx >> 6) & 3;
    const int jz = o_idx >> 8;
    const float scale = 0.125f;

    if (t < 8) Buf2[2560 + t] = (bf16)0.f;   // zero region (never overwritten)
    const bf16* Zbuf = &Buf2[2560];

    // A-frag of centered Wt^T: one 16B load (quad>=2 slots are stored zeros).
    bf16x8 a_wt = *(const bf16x8*)&WtcT[l15 * 32 + quad * 8];
    float gq[4], bq[4];
#pragma unroll
    for (int r = 0; r < 4; ++r) { gq[r] = gamma[quad * 4 + r]; bq[r] = beta[quad * 4 + r]; }

    bf16x8 qa[2][2];
    float invl[2][4];
#pragma unroll
    for (int hh = 0; hh < 2; ++hh) {
        int h = wv * 2 + hh;
        const bf16* qp = Qb + (size_t)(b * 1024 + i0 + l15) * 1024 + h * 64 + quad * 8;
        qa[hh][0] = *(const bf16x8*)qp;
        qa[hh][1] = *(const bf16x8*)(qp + 32);
#pragma unroll
        for (int r = 0; r < 4; ++r)
            invl[hh][r] = 1.f / L[(size_t)(b * 16 + h) * 1024 + i0 + quad * 4 + r];
    }

    const bf16* Kbase = Kb + (size_t)b * 1024 * 1024;
    const bf16* Vbase = Vt + (size_t)b * 16 * 64 * 1024;
    floatx4 o[2][4] = {};

    for (int jt = 0; jt < 16; ++jt) {
        const int j0 = jz * 512 + jt * 32;
        // (a) S -> w -> Buf1 (packed bf16x2 for the wave's head pair)
#pragma unroll
        for (int ns = 0; ns < 2; ++ns) {
            floatx4 cw[2];
#pragma unroll
            for (int hh = 0; hh < 2; ++hh) {
                int h = wv * 2 + hh;
                const bf16* kp = Kbase + (size_t)(j0 + ns * 16 + l15) * 1024 + h * 64 + quad * 8;
                floatx4 c = {0.f, 0.f, 0.f, 0.f};
                c = MFMA_BF16(qa[hh][0], *(const bf16x8*)kp, c);
                c = MFMA_BF16(qa[hh][1], *(const bf16x8*)(kp + 32), c);
                cw[hh] = c;
            }
#pragma unroll
            for (int r = 0; r < 4; ++r) {
                bf16x2 pk = {(bf16)(__expf(cw[0][r] * scale) * invl[0][r]),
                             (bf16)(__expf(cw[1][r] * scale) * invl[1][r])};
                *(bf16x2*)&Buf1[((quad * 4 + r) * 32 + ns * 16 + l15) * 20 + wv * 2] = pk;
            }
        }
        __syncthreads();
        // (b) mix (C[g][point]) + LN over g (mean is exactly 0 by centering)
#pragma unroll
        for (int grp = 0; grp < 4; ++grp) {
            int gi = wv * 4 + grp, ig = gi >> 1, jb = (gi & 1) * 16;
            int p = ig * 32 + jb + l15;
            const bf16* src = (quad < 2) ? &Buf1[p * 20 + quad * 8] : Zbuf;
            floatx4 c = {0.f, 0.f, 0.f, 0.f};
            c = MFMA_BF16(a_wt, *(const bf16x8*)src, c);
            float s2 = c[0] * c[0] + c[1] * c[1] + c[2] * c[2] + c[3] * c[3];
            s2 += __shfl_xor(s2, 16);
            s2 += __shfl_xor(s2, 32);
            float rs = rsqrtf(s2 * 0.0625f + 1e-5f);
#pragma unroll
            for (int r = 0; r < 4; ++r) {
                float w2 = c[r] * rs * gq[r] + bq[r];
                Buf2[(quad * 4 + r) * 640 + (quad & 1) * 8 + ig * 40 + jb + l15] = (bf16)w2;
            }
        }
        __syncthreads();
        // (c) PV: O[i][d] += w2[i][jl] * V[jl][d]
#pragma unroll
        for (int hh = 0; hh < 2; ++hh) {
            int g = wv * 2 + hh;
            bf16x8 a = *(bf16x8*)&Buf2[g * 640 + ((g >> 2) & 1) * 8 + l15 * 40 + quad * 8];
#pragma unroll
            for (int dt = 0; dt < 4; ++dt) {
                const bf16* vp = Vbase + (size_t)(g * 64 + dt * 16 + l15) * 1024 + j0 + quad * 8;
                o[hh][dt] = MFMA_BF16(a, *(const bf16x8*)vp, o[hh][dt]);
            }
        }
    }
#pragma unroll
    for (int hh = 0; hh < 2; ++hh) {
        int g = wv * 2 + hh;
#pragma unroll
        for (int dt = 0; dt < 4; ++dt)
#pragma unroll
            for (int r = 0; r < 4; ++r)
                atomicAdd(&out[(size_t)(b * 1024 + i0 + quad * 4 + r) * 1024 +
                               g * 64 + dt * 16 + l15], o[hh][dt][r]);
    }
}

extern "C" void kernel_launch(void* const* d_in, const int* in_sizes, int n_in,
                              void* d_out, int out_size, void* d_ws, size_t ws_size,
                              hipStream_t stream) {
    const float* x     = (const float*)d_in[0];
    const float* ctx   = (const float*)d_in[1];
    const float* Wq    = (const float*)d_in[2];
    const float* Wkv   = (const float*)d_in[3];
    const float* Wt    = (const float*)d_in[4];
    const float* gamma = (const float*)d_in[5];
    const float* beta  = (const float*)d_in[6];
    float* out = (float*)d_out;

    // ws layout (bf16 els): xb 4M | ctxb 4M | WqT 1M | WkvT 2M | Qb 4M | Kb 4M |
    //                       Vr 4M | Vt 4M | L (64K fp32)   => ~54.25 MB
    // WtcT (512 bf16) reuses the head of Vr: Vr is dead after vtrans_kernel.
    bf16* xb   = (bf16*)d_ws;
    bf16* cb   = xb + (size_t)4 * 1024 * 1024;
    bf16* WqT  = cb + (size_t)4 * 1024 * 1024;
    bf16* WkvT = WqT + (size_t)1024 * 1024;
    bf16* Qb   = WkvT + (size_t)2048 * 1024;
    bf16* Kb   = Qb + (size_t)4 * 1024 * 1024;
    bf16* Vr   = Kb + (size_t)4 * 1024 * 1024;
    bf16* Vt   = Vr + (size_t)4 * 1024 * 1024;
    float* L   = (float*)(Vt + (size_t)4 * 1024 * 1024);
    bf16* WtcT = Vr;

    hipMemsetAsync(L, 0, (size_t)4 * 16 * 1024 * sizeof(float), stream);
    hipMemsetAsync(out, 0, (size_t)out_size * sizeof(float), stream);

    cvt_kernel<<<2048, 256, 0, stream>>>(x, xb, 524288);
    cvt_kernel<<<2048, 256, 0, stream>>>(ctx, cb, 524288);
    trans_kernel<<<dim3(32, 32), 256, 0, stream>>>(Wq, WqT, 1024, 1024);
    trans_kernel<<<dim3(64, 32), 256, 0, stream>>>(Wkv, WkvT, 1024, 2048);

    gemm128<0><<<dim3(8, 32), 256, 0, stream>>>(xb, WqT, Qb, nullptr, 1024);
    gemm128<1><<<dim3(16, 32), 256, 0, stream>>>(cb, WkvT, Kb, Vr, 2048);
    vtrans_kernel<<<dim3(32, 128), 256, 0, stream>>>(Vr, Vt);
    prep_wt_kernel<<<1, 256, 0, stream>>>(Wt, WtcT);

    denom_kernel<<<dim3(32, 4, 16), 256, 0, stream>>>(Qb, Kb, L);
    attn_kernel<<<dim3(64, 4, 2), 512, 0, stream>>>(Qb, Kb, Vt, L, WtcT, gamma, beta, out);
}